// Round 1
// baseline (933.837 us; speedup 1.0000x reference)
//
#include <hip/hip_runtime.h>
#include <hip/hip_bf16.h>
#include <math.h>

// Problem dims
#define B_SZ 16
#define L_SZ 8192
#define DM   256
#define SS   256
#define FF   1024
#define M_SZ (B_SZ * L_SZ)      // 131072 rows
#define TCH  256                // scan chunk length
#define NCH  (L_SZ / TCH)       // 32 chunks per batch

// GEMM tile
#define BM 128
#define BN 128
#define BK 32

typedef __bf16 bf16x8 __attribute__((ext_vector_type(8)));
typedef float  f32x4  __attribute__((ext_vector_type(4)));

// ---------------------------------------------------------------- async 16B global->LDS
__device__ __forceinline__ void gld_lds16(const __bf16* g, __bf16* l) {
  __builtin_amdgcn_global_load_lds(
      (const __attribute__((address_space(1))) unsigned int*)g,
      (__attribute__((address_space(3))) unsigned int*)l, 16, 0, 0);
}

// ---------------------------------------------------------------- weight prep
// Wb   (512 x 256)  rows interleaved: row 2s = gamma*B_re[s], row 2s+1 = gamma*B_im[s]
// Wz   (256 x 768)  cols [2s]=C_re[o][s], [2s+1]=-C_im[o][s], [512+d]=D[o][d]
// Wfc  (1024 x 256) = W_fc^T
// Wp   (256 x 1024) = W_proj^T
// lam  (2*256)      interleaved (re, im)
__global__ void prep_kernel(const float* __restrict__ nu_log, const float* __restrict__ th_log,
                            const float* __restrict__ ga_log,
                            const float* __restrict__ B_re, const float* __restrict__ B_im,
                            const float* __restrict__ C_re, const float* __restrict__ C_im,
                            const float* __restrict__ Dmat,
                            const float* __restrict__ W_fc, const float* __restrict__ W_proj,
                            __bf16* __restrict__ Wb, __bf16* __restrict__ Wz,
                            __bf16* __restrict__ Wfc, __bf16* __restrict__ Wp,
                            float* __restrict__ lam)
{
  const int idx = blockIdx.x * 256 + threadIdx.x;   // 0 .. 262143
  if (idx < SS) {
    float la = expf(-expf(nu_log[idx]));
    float th = expf(th_log[idx]);
    lam[2*idx]   = la * cosf(th);
    lam[2*idx+1] = la * sinf(th);
  }
  if (idx < SS*DM) {
    int s = idx >> 8, d = idx & 255;
    float eg = expf(ga_log[s]);
    Wb[(size_t)(2*s)*DM + d]   = (__bf16)(B_re[idx] * eg);
    Wb[(size_t)(2*s+1)*DM + d] = (__bf16)(B_im[idx] * eg);
  }
  if (idx < DM*SS) {
    int o = idx >> 8, s = idx & 255;
    Wz[(size_t)o*768 + 2*s]     = (__bf16)( C_re[idx]);
    Wz[(size_t)o*768 + 2*s + 1] = (__bf16)(-C_im[idx]);
    Wz[(size_t)o*768 + 512 + s] = (__bf16)( Dmat[idx]);   // s acts as d here
  }
  if (idx < FF*DM) {
    int f = idx >> 8, d = idx & 255;                 // Wfc[f][d] = W_fc[d][f]
    Wfc[idx] = (__bf16)(W_fc[(size_t)d*FF + f]);
    int o = idx >> 10, f2 = idx & 1023;              // Wp[o][f2] = W_proj[f2][o]
    Wp[idx] = (__bf16)(W_proj[(size_t)f2*DM + o]);
  }
}

// ---------------------------------------------------------------- x (fp32) -> bf16 into S_all cols [512,768)
__global__ __launch_bounds__(256) void convert_x(const float* __restrict__ x, __bf16* __restrict__ S_all)
{
  const long i = ((long)blockIdx.x * 256 + threadIdx.x) * 4;  // over 33554432
  float4 v = *(const float4*)(x + i);
  const long m = i >> 8;
  const int  d = (int)(i & 255);
  union { __bf16 h[4]; uint2 u; } pk;
  pk.h[0] = (__bf16)v.x; pk.h[1] = (__bf16)v.y; pk.h[2] = (__bf16)v.z; pk.h[3] = (__bf16)v.w;
  *(uint2*)(S_all + m*768 + 512 + d) = pk.u;
}

// ---------------------------------------------------------------- bf16 MFMA GEMM, B^T (N,K) weights
// MODE 0: store f32            (Bu)
// MODE 1: store bf16           (z)
// MODE 2: bias + exact gelu -> bf16  (h)
// MODE 3: bias + residual  -> f32    (final out)
template<int K, int LDA, int LDC, int MODE>
__global__ __launch_bounds__(256, 2) void gemm_bt(const __bf16* __restrict__ A,
                                                  const __bf16* __restrict__ Bw,
                                                  void* __restrict__ Cout,
                                                  const float* __restrict__ bias,
                                                  const float* __restrict__ resid)
{
  __shared__ __attribute__((aligned(16))) __bf16 sA[BM * BK];
  __shared__ __attribute__((aligned(16))) __bf16 sB[BN * BK];

  const int tid  = threadIdx.x;
  const int lane = tid & 63;
  const int wave = tid >> 6;
  const int wm = (wave & 1) * 64;
  const int wn = (wave >> 1) * 64;
  const long m0 = (long)blockIdx.x * BM;
  const long n0 = (long)blockIdx.y * BN;

  f32x4 acc[4][4] = {};

  const int r  = tid >> 2;         // 0..63 (row within 64-row half)
  const int c8 = (tid & 3) * 8;    // k element offset of this thread's 16B chunk
  const __bf16* gA = A  + (m0 + r) * (long)LDA + c8;
  const __bf16* gB = Bw + (n0 + r) * (long)K   + c8;

  const int ar = lane & 15;
  const int ak = (lane >> 4) * 8;

  for (int k0 = 0; k0 < K; k0 += BK) {
    gld_lds16(gA,            &sA[tid * 8]);
    gld_lds16(gA + 64 * (long)LDA, &sA[2048 + tid * 8]);
    gld_lds16(gB,            &sB[tid * 8]);
    gld_lds16(gB + 64 * (long)K,   &sB[2048 + tid * 8]);
    gA += BK; gB += BK;
    __syncthreads();   // compiler emits vmcnt(0) drain before barrier

    bf16x8 af[4], bg[4];
    #pragma unroll
    for (int i = 0; i < 4; ++i)
      af[i] = *(const bf16x8*)&sA[(wm + i * 16 + ar) * BK + ak];
    #pragma unroll
    for (int j = 0; j < 4; ++j)
      bg[j] = *(const bf16x8*)&sB[(wn + j * 16 + ar) * BK + ak];
    #pragma unroll
    for (int i = 0; i < 4; ++i)
      #pragma unroll
      for (int j = 0; j < 4; ++j)
        acc[i][j] = __builtin_amdgcn_mfma_f32_16x16x32_bf16(af[i], bg[j], acc[i][j], 0, 0, 0);
    __syncthreads();
  }

  // Epilogue: D row = (lane>>4)*4 + reg, col = lane&15   [measured m89/m91]
  const int col_l = lane & 15;
  const int row_l = (lane >> 4) * 4;
  #pragma unroll
  for (int i = 0; i < 4; ++i) {
    #pragma unroll
    for (int j = 0; j < 4; ++j) {
      const long row = m0 + wm + i * 16 + row_l;
      const long col = n0 + wn + j * 16 + col_l;
      #pragma unroll
      for (int rr = 0; rr < 4; ++rr) {
        const float v = acc[i][j][rr];
        const long idx = (row + rr) * (long)LDC + col;
        if constexpr (MODE == 0) {
          ((float*)Cout)[idx] = v;
        } else if constexpr (MODE == 1) {
          ((__bf16*)Cout)[idx] = (__bf16)v;
        } else if constexpr (MODE == 2) {
          const float t = v + bias[col];
          const float g = 0.5f * t * (1.0f + erff(t * 0.70710678118654752f));
          ((__bf16*)Cout)[idx] = (__bf16)g;
        } else {
          ((float*)Cout)[idx] = v + bias[col] + resid[idx];
        }
      }
    }
  }
}

// ---------------------------------------------------------------- scan kernels
#define CSTEP(v) { float nr_ = fmaf(lr, sr, fmaf(-li, si, (v).x)); \
                   float ni_ = fmaf(lr, si, fmaf( li, sr, (v).y)); sr = nr_; si = ni_; }

// Pass A: per-chunk carry with s_init = 0. Bu layout: (M, 512) f32, col 2s=re, 2s+1=im.
__global__ __launch_bounds__(256) void scan_carry(const float* __restrict__ Bu,
                                                  const float* __restrict__ lam,
                                                  float2* __restrict__ carr)
{
  const int s  = threadIdx.x;
  const int bc = blockIdx.x;                       // b*NCH + c ; rows bc*256 ..
  const float lr = lam[2*s], li = lam[2*s+1];
  const float2* bu = (const float2*)(Bu + (size_t)bc * (TCH * 512)) + s;  // row stride 256 float2
  float sr = 0.f, si = 0.f;
  float2 v0 = bu[0], v1 = bu[256], v2 = bu[512], v3 = bu[768];
  for (int t = 0; t < TCH - 4; t += 4) {
    float2 n0 = bu[(t+4)*256], n1 = bu[(t+5)*256], n2 = bu[(t+6)*256], n3 = bu[(t+7)*256];
    CSTEP(v0); CSTEP(v1); CSTEP(v2); CSTEP(v3);
    v0 = n0; v1 = n1; v2 = n2; v3 = n3;
  }
  CSTEP(v0); CSTEP(v1); CSTEP(v2); CSTEP(v3);
  carr[(size_t)bc * 256 + s] = make_float2(sr, si);
}

// Pass B: exclusive prefix over chunks, operator p' = lam^T * p + carry
__global__ __launch_bounds__(256) void scan_prefix(const float2* __restrict__ carr,
                                                   const float* __restrict__ lam,
                                                   float2* __restrict__ pre)
{
  const int s = threadIdx.x;
  const int b = blockIdx.x;
  const float lr0 = lam[2*s], li0 = lam[2*s+1];
  float ar = lr0, ai = li0;                        // lam^(2^k) by squaring: T=256=2^8
  #pragma unroll
  for (int i = 0; i < 8; ++i) { float nr = ar*ar - ai*ai, ni = 2.f*ar*ai; ar = nr; ai = ni; }
  float pr = 0.f, pi = 0.f;
  for (int c = 0; c < NCH; ++c) {
    const size_t off = (size_t)(b * NCH + c) * 256 + s;
    pre[off] = make_float2(pr, pi);
    float2 cv = carr[off];
    float nr = fmaf(ar, pr, fmaf(-ai, pi, cv.x));
    float ni = fmaf(ar, pi, fmaf( ai, pr, cv.y));
    pr = nr; pi = ni;
  }
}

// Pass C: re-scan with init = prefix, write inclusive states as bf16 into S_all cols [0,512)
__global__ __launch_bounds__(256) void scan_apply(const float* __restrict__ Bu,
                                                  const float* __restrict__ lam,
                                                  const float2* __restrict__ pre,
                                                  __bf16* __restrict__ S_all)
{
  const int s  = threadIdx.x;
  const int bc = blockIdx.x;
  const float lr = lam[2*s], li = lam[2*s+1];
  float2 p = pre[(size_t)bc * 256 + s];
  float sr = p.x, si = p.y;
  const float2* bu = (const float2*)(Bu + (size_t)bc * (TCH * 512)) + s;
  __bf16* outp = S_all + (size_t)bc * (TCH * 768) + 2 * s;
  #define APSTEP(v, t) { CSTEP(v); \
    union { __bf16 h[2]; unsigned int u; } pk_; pk_.h[0] = (__bf16)sr; pk_.h[1] = (__bf16)si; \
    *(unsigned int*)(outp + (size_t)(t) * 768) = pk_.u; }
  float2 v0 = bu[0], v1 = bu[256], v2 = bu[512], v3 = bu[768];
  for (int t = 0; t < TCH - 4; t += 4) {
    float2 n0 = bu[(t+4)*256], n1 = bu[(t+5)*256], n2 = bu[(t+6)*256], n3 = bu[(t+7)*256];
    APSTEP(v0, t); APSTEP(v1, t+1); APSTEP(v2, t+2); APSTEP(v3, t+3);
    v0 = n0; v1 = n1; v2 = n2; v3 = n3;
  }
  { const int t = TCH - 4; APSTEP(v0, t); APSTEP(v1, t+1); APSTEP(v2, t+2); APSTEP(v3, t+3); }
  #undef APSTEP
}

// ---------------------------------------------------------------- launch
extern "C" void kernel_launch(void* const* d_in, const int* in_sizes, int n_in,
                              void* d_out, int out_size, void* d_ws, size_t ws_size,
                              hipStream_t stream)
{
  const float* x      = (const float*)d_in[0];
  const float* nu_log = (const float*)d_in[1];
  const float* th_log = (const float*)d_in[2];
  const float* ga_log = (const float*)d_in[3];
  const float* B_re   = (const float*)d_in[4];
  const float* B_im   = (const float*)d_in[5];
  const float* C_re   = (const float*)d_in[6];
  const float* C_im   = (const float*)d_in[7];
  const float* Dmat   = (const float*)d_in[8];
  const float* W_fc   = (const float*)d_in[9];
  const float* b_fc   = (const float*)d_in[10];
  const float* W_proj = (const float*)d_in[11];
  const float* b_proj = (const float*)d_in[12];

  // ws layout (bytes):
  //   S_all : (M, 768) bf16  @ 0          201326592   [states interleaved | x_bf16]
  //   Bu/h  : (M, 512) f32 == (M,1024) bf16 @ 201326592  268435456
  //   Wb/Wz/Wfc/Wp/lam       @ 469762048  ~1.7 MB
  char* ws = (char*)d_ws;
  __bf16* S_all = (__bf16*)(ws);
  float*  Bu    = (float*) (ws + 201326592);
  __bf16* Hbuf  = (__bf16*)(ws + 201326592);
  __bf16* Wb    = (__bf16*)(ws + 469762048);
  __bf16* Wz    = (__bf16*)(ws + 470024192);
  __bf16* Wfc   = (__bf16*)(ws + 470417408);
  __bf16* Wp    = (__bf16*)(ws + 470941696);
  float*  lam   = (float*) (ws + 471465984);
  if (ws_size < 471468032ULL) return;  // insufficient scratch: fail visibly

  // d_out (134 MB) doubles as scratch before the final GEMM overwrites all of it:
  char* ob = (char*)d_out;
  __bf16* Zbuf = (__bf16*)ob;                    // (M,256) bf16 = 67 MB
  float2* carr = (float2*)(ob + 67108864);       // 1 MB
  float2* pre  = (float2*)(ob + 68157440);       // 1 MB

  prep_kernel<<<1024, 256, 0, stream>>>(nu_log, th_log, ga_log, B_re, B_im,
                                        C_re, C_im, Dmat, W_fc, W_proj,
                                        Wb, Wz, Wfc, Wp, lam);
  convert_x<<<M_SZ * DM / (256 * 4), 256, 0, stream>>>(x, S_all);

  // Bu = x @ [gamma*B_re ; gamma*B_im]^T   (M,512) f32
  gemm_bt<256, 768, 512, 0><<<dim3(M_SZ / BM, 4), 256, 0, stream>>>(S_all + 512, Wb, Bu, nullptr, nullptr);

  scan_carry <<<B_SZ * NCH, 256, 0, stream>>>(Bu, lam, carr);
  scan_prefix<<<B_SZ,       256, 0, stream>>>(carr, lam, pre);
  scan_apply <<<B_SZ * NCH, 256, 0, stream>>>(Bu, lam, pre, S_all);

  // z = Re(C s) + x D^T   -> bf16
  gemm_bt<768, 768, 256, 1><<<dim3(M_SZ / BM, 2), 256, 0, stream>>>(S_all, Wz, Zbuf, nullptr, nullptr);
  // h = gelu(z W_fc + b_fc) -> bf16 (reuses Bu region)
  gemm_bt<256, 256, 1024, 2><<<dim3(M_SZ / BM, 8), 256, 0, stream>>>(Zbuf, Wfc, Hbuf, b_fc, nullptr);
  // out = h W_proj + b_proj + x -> f32
  gemm_bt<1024, 1024, 256, 3><<<dim3(M_SZ / BM, 2), 256, 0, stream>>>(Hbuf, Wp, d_out, b_proj, x);
}

// Round 2
// 792.307 us; speedup vs baseline: 1.1786x; 1.1786x over previous
//
#include <hip/hip_runtime.h>
#include <hip/hip_bf16.h>
#include <math.h>

// Problem dims
#define B_SZ 16
#define L_SZ 8192
#define DM   256
#define SS   256
#define FF   1024
#define M_SZ (B_SZ * L_SZ)      // 131072 rows
#define TCH  128                // scan chunk length
#define NCH  (L_SZ / TCH)       // 64 chunks per batch

// GEMM tile
#define BM 128
#define BN 128
#define BK 32

typedef __bf16 bf16x8 __attribute__((ext_vector_type(8)));
typedef float  f32x4  __attribute__((ext_vector_type(4)));

// ---------------------------------------------------------------- async 16B global->LDS
__device__ __forceinline__ void gld_lds16(const __bf16* g, __bf16* l) {
  __builtin_amdgcn_global_load_lds(
      (const __attribute__((address_space(1))) unsigned int*)g,
      (__attribute__((address_space(3))) unsigned int*)l, 16, 0, 0);
}

// ---------------------------------------------------------------- weight prep
__global__ void prep_kernel(const float* __restrict__ nu_log, const float* __restrict__ th_log,
                            const float* __restrict__ ga_log,
                            const float* __restrict__ B_re, const float* __restrict__ B_im,
                            const float* __restrict__ C_re, const float* __restrict__ C_im,
                            const float* __restrict__ Dmat,
                            const float* __restrict__ W_fc, const float* __restrict__ W_proj,
                            __bf16* __restrict__ Wb, __bf16* __restrict__ Wz,
                            __bf16* __restrict__ Wfc, __bf16* __restrict__ Wp,
                            float* __restrict__ lam)
{
  const int idx = blockIdx.x * 256 + threadIdx.x;   // 0 .. 262143
  if (idx < SS) {
    float la = expf(-expf(nu_log[idx]));
    float th = expf(th_log[idx]);
    lam[2*idx]   = la * cosf(th);
    lam[2*idx+1] = la * sinf(th);
  }
  if (idx < SS*DM) {
    int s = idx >> 8, d = idx & 255;
    float eg = expf(ga_log[s]);
    Wb[(size_t)(2*s)*DM + d]   = (__bf16)(B_re[idx] * eg);
    Wb[(size_t)(2*s+1)*DM + d] = (__bf16)(B_im[idx] * eg);
  }
  if (idx < DM*SS) {
    int o = idx >> 8, s = idx & 255;
    Wz[(size_t)o*768 + 2*s]     = (__bf16)( C_re[idx]);
    Wz[(size_t)o*768 + 2*s + 1] = (__bf16)(-C_im[idx]);
    Wz[(size_t)o*768 + 512 + s] = (__bf16)( Dmat[idx]);   // s acts as d here
  }
  if (idx < FF*DM) {
    int f = idx >> 8, d = idx & 255;                 // Wfc[f][d] = W_fc[d][f]
    Wfc[idx] = (__bf16)(W_fc[(size_t)d*FF + f]);
    int o = idx >> 10, f2 = idx & 1023;              // Wp[o][f2] = W_proj[f2][o]
    Wp[idx] = (__bf16)(W_proj[(size_t)f2*DM + o]);
  }
}

// ---------------------------------------------------------------- x (fp32) -> bf16 into S_all cols [512,768)
__global__ __launch_bounds__(256) void convert_x(const float* __restrict__ x, __bf16* __restrict__ S_all)
{
  const long i = ((long)blockIdx.x * 256 + threadIdx.x) * 4;  // over 33554432
  float4 v = *(const float4*)(x + i);
  const long m = i >> 8;
  const int  d = (int)(i & 255);
  union { __bf16 h[4]; uint2 u; } pk;
  pk.h[0] = (__bf16)v.x; pk.h[1] = (__bf16)v.y; pk.h[2] = (__bf16)v.z; pk.h[3] = (__bf16)v.w;
  *(uint2*)(S_all + m*768 + 512 + d) = pk.u;
}

// ---------------------------------------------------------------- bf16 MFMA GEMM, B^T (N,K) weights
// 1D grid with L2-locality swizzle: band of 16 M-tiles, N fastest inside a band,
// so ~concurrent blocks share one A band (kills the NTx A re-fetch from HBM).
// MODE 1: store bf16
// MODE 2: bias + exact gelu -> bf16
// MODE 3: bias + residual(f32) -> f32
template<int K, int LDA, int LDC, int MODE, int NT>
__global__ __launch_bounds__(256, 2) void gemm_bt(const __bf16* __restrict__ A,
                                                  const __bf16* __restrict__ Bw,
                                                  void* __restrict__ Cout,
                                                  const float* __restrict__ bias,
                                                  const float* __restrict__ resid)
{
  __shared__ __attribute__((aligned(16))) __bf16 sA[BM * BK];
  __shared__ __attribute__((aligned(16))) __bf16 sB[BN * BK];

  const int tid  = threadIdx.x;
  const int lane = tid & 63;
  const int wave = tid >> 6;
  const int wm = (wave & 1) * 64;
  const int wn = (wave >> 1) * 64;

  constexpr int PER = 16 * NT;              // blocks per super-band (power of 2)
  const int blk = blockIdx.x;
  const int sb  = blk / PER;
  const int rem = blk & (PER - 1);
  const long m0 = (long)((sb << 4) + (rem & 15)) * BM;
  const long n0 = (long)(rem >> 4) * BN;

  f32x4 acc[4][4] = {};

  const int r  = tid >> 2;         // 0..63 (row within 64-row half)
  const int c8 = (tid & 3) * 8;    // k element offset of this thread's 16B chunk
  const __bf16* gA = A  + (m0 + r) * (long)LDA + c8;
  const __bf16* gB = Bw + (n0 + r) * (long)K   + c8;

  const int ar = lane & 15;
  const int ak = (lane >> 4) * 8;

  for (int k0 = 0; k0 < K; k0 += BK) {
    gld_lds16(gA,                  &sA[tid * 8]);
    gld_lds16(gA + 64 * (long)LDA, &sA[2048 + tid * 8]);
    gld_lds16(gB,                  &sB[tid * 8]);
    gld_lds16(gB + 64 * (long)K,   &sB[2048 + tid * 8]);
    gA += BK; gB += BK;
    __syncthreads();

    bf16x8 af[4], bg[4];
    #pragma unroll
    for (int i = 0; i < 4; ++i)
      af[i] = *(const bf16x8*)&sA[(wm + i * 16 + ar) * BK + ak];
    #pragma unroll
    for (int j = 0; j < 4; ++j)
      bg[j] = *(const bf16x8*)&sB[(wn + j * 16 + ar) * BK + ak];
    #pragma unroll
    for (int i = 0; i < 4; ++i)
      #pragma unroll
      for (int j = 0; j < 4; ++j)
        acc[i][j] = __builtin_amdgcn_mfma_f32_16x16x32_bf16(af[i], bg[j], acc[i][j], 0, 0, 0);
    __syncthreads();
  }

  // Epilogue: D row = (lane>>4)*4 + reg, col = lane&15   [measured m89/m91]
  const int col_l = lane & 15;
  const int row_l = (lane >> 4) * 4;
  #pragma unroll
  for (int i = 0; i < 4; ++i) {
    #pragma unroll
    for (int j = 0; j < 4; ++j) {
      const long row = m0 + wm + i * 16 + row_l;
      const long col = n0 + wn + j * 16 + col_l;
      #pragma unroll
      for (int rr = 0; rr < 4; ++rr) {
        const float v = acc[i][j][rr];
        const long idx = (row + rr) * (long)LDC + col;
        if constexpr (MODE == 1) {
          ((__bf16*)Cout)[idx] = (__bf16)v;
        } else if constexpr (MODE == 2) {
          const float t = v + bias[col];
          const float g = 0.5f * t * (1.0f + erff(t * 0.70710678118654752f));
          ((__bf16*)Cout)[idx] = (__bf16)g;
        } else {
          ((float*)Cout)[idx] = v + bias[col] + resid[idx];
        }
      }
    }
  }
}

// ---------------------------------------------------------------- scan kernels
// Bu layout: (M, 512) bf16, col 2s=re, 2s+1=im. Thread s loads 4B (2 bf16) per row.
#define CSTEP(vr, vi) { float nr_ = fmaf(lr, sr, fmaf(-li, si, (vr))); \
                        float ni_ = fmaf(lr, si, fmaf( li, sr, (vi))); sr = nr_; si = ni_; }

union bupk { unsigned int u; __bf16 h[2]; };

// Pass A: per-chunk carry with s_init = 0.
__global__ __launch_bounds__(256) void scan_carry(const __bf16* __restrict__ Bu,
                                                  const float* __restrict__ lam,
                                                  float2* __restrict__ carr)
{
  const int s  = threadIdx.x;
  const int bc = blockIdx.x;                       // b*NCH + c
  const float lr = lam[2*s], li = lam[2*s+1];
  const unsigned int* bu = (const unsigned int*)(Bu + (size_t)bc * (TCH * 512)) + s; // row stride 256 uints
  float sr = 0.f, si = 0.f;
  bupk v0, v1, v2, v3;
  v0.u = bu[0]; v1.u = bu[256]; v2.u = bu[512]; v3.u = bu[768];
  for (int t = 0; t < TCH - 4; t += 4) {
    bupk n0, n1, n2, n3;
    n0.u = bu[(t+4)*256]; n1.u = bu[(t+5)*256]; n2.u = bu[(t+6)*256]; n3.u = bu[(t+7)*256];
    CSTEP((float)v0.h[0], (float)v0.h[1]); CSTEP((float)v1.h[0], (float)v1.h[1]);
    CSTEP((float)v2.h[0], (float)v2.h[1]); CSTEP((float)v3.h[0], (float)v3.h[1]);
    v0 = n0; v1 = n1; v2 = n2; v3 = n3;
  }
  CSTEP((float)v0.h[0], (float)v0.h[1]); CSTEP((float)v1.h[0], (float)v1.h[1]);
  CSTEP((float)v2.h[0], (float)v2.h[1]); CSTEP((float)v3.h[0], (float)v3.h[1]);
  carr[(size_t)bc * 256 + s] = make_float2(sr, si);
}

// Pass B: exclusive prefix over chunks, operator p' = lam^TCH * p + carry
__global__ __launch_bounds__(256) void scan_prefix(const float2* __restrict__ carr,
                                                   const float* __restrict__ lam,
                                                   float2* __restrict__ pre)
{
  const int s = threadIdx.x;
  const int b = blockIdx.x;
  float ar = lam[2*s], ai = lam[2*s+1];            // lam^TCH by squaring: TCH=128=2^7
  #pragma unroll
  for (int i = 0; i < 7; ++i) { float nr = ar*ar - ai*ai, ni = 2.f*ar*ai; ar = nr; ai = ni; }
  float pr = 0.f, pi = 0.f;
  for (int c = 0; c < NCH; ++c) {
    const size_t off = (size_t)(b * NCH + c) * 256 + s;
    pre[off] = make_float2(pr, pi);
    float2 cv = carr[off];
    float nr = fmaf(ar, pr, fmaf(-ai, pi, cv.x));
    float ni = fmaf(ar, pi, fmaf( ai, pr, cv.y));
    pr = nr; pi = ni;
  }
}

// Pass C: re-scan with init = prefix, write inclusive states as bf16 into S_all cols [0,512)
__global__ __launch_bounds__(256) void scan_apply(const __bf16* __restrict__ Bu,
                                                  const float* __restrict__ lam,
                                                  const float2* __restrict__ pre,
                                                  __bf16* __restrict__ S_all)
{
  const int s  = threadIdx.x;
  const int bc = blockIdx.x;
  const float lr = lam[2*s], li = lam[2*s+1];
  float2 p = pre[(size_t)bc * 256 + s];
  float sr = p.x, si = p.y;
  const unsigned int* bu = (const unsigned int*)(Bu + (size_t)bc * (TCH * 512)) + s;
  __bf16* outp = S_all + (size_t)bc * (TCH * 768) + 2 * s;
  #define APSTEP(v, t) { CSTEP((float)(v).h[0], (float)(v).h[1]); \
    union { __bf16 h[2]; unsigned int u; } pk_; pk_.h[0] = (__bf16)sr; pk_.h[1] = (__bf16)si; \
    *(unsigned int*)(outp + (size_t)(t) * 768) = pk_.u; }
  bupk v0, v1, v2, v3;
  v0.u = bu[0]; v1.u = bu[256]; v2.u = bu[512]; v3.u = bu[768];
  for (int t = 0; t < TCH - 4; t += 4) {
    bupk n0, n1, n2, n3;
    n0.u = bu[(t+4)*256]; n1.u = bu[(t+5)*256]; n2.u = bu[(t+6)*256]; n3.u = bu[(t+7)*256];
    APSTEP(v0, t); APSTEP(v1, t+1); APSTEP(v2, t+2); APSTEP(v3, t+3);
    v0 = n0; v1 = n1; v2 = n2; v3 = n3;
  }
  { const int t = TCH - 4; APSTEP(v0, t); APSTEP(v1, t+1); APSTEP(v2, t+2); APSTEP(v3, t+3); }
  #undef APSTEP
}

// ---------------------------------------------------------------- launch
extern "C" void kernel_launch(void* const* d_in, const int* in_sizes, int n_in,
                              void* d_out, int out_size, void* d_ws, size_t ws_size,
                              hipStream_t stream)
{
  const float* x      = (const float*)d_in[0];
  const float* nu_log = (const float*)d_in[1];
  const float* th_log = (const float*)d_in[2];
  const float* ga_log = (const float*)d_in[3];
  const float* B_re   = (const float*)d_in[4];
  const float* B_im   = (const float*)d_in[5];
  const float* C_re   = (const float*)d_in[6];
  const float* C_im   = (const float*)d_in[7];
  const float* Dmat   = (const float*)d_in[8];
  const float* W_fc   = (const float*)d_in[9];
  const float* b_fc   = (const float*)d_in[10];
  const float* W_proj = (const float*)d_in[11];
  const float* b_proj = (const float*)d_in[12];

  // ws layout (bytes):
  //   S_all : (M, 768) bf16 @ 0            201326592  [states interleaved | x_bf16]
  //   Bu    : (M, 512) bf16 @ 201326592    134217728  (dead after scan_apply)
  //   Hbuf  : (M,1024) bf16 @ 201326592    268435456  (overlaps Bu; written by gemm3 after Bu dead)
  //   Wb/Wz/Wfc/Wp/lam      @ 469762048    ~1.7 MB
  char* ws = (char*)d_ws;
  __bf16* S_all = (__bf16*)(ws);
  __bf16* Bu    = (__bf16*)(ws + 201326592);
  __bf16* Hbuf  = (__bf16*)(ws + 201326592);
  __bf16* Wb    = (__bf16*)(ws + 469762048);
  __bf16* Wz    = (__bf16*)(ws + 470024192);
  __bf16* Wfc   = (__bf16*)(ws + 470417408);
  __bf16* Wp    = (__bf16*)(ws + 470941696);
  float*  lam   = (float*) (ws + 471465984);
  if (ws_size < 471468032ULL) return;  // insufficient scratch: fail visibly

  // d_out (134 MB) doubles as scratch before the final GEMM overwrites all of it:
  char* ob = (char*)d_out;
  __bf16* Zbuf = (__bf16*)ob;                    // (M,256) bf16 = 67108864 B
  float2* carr = (float2*)(ob + 67108864);       // 16*64*256*8 = 2 MB
  float2* pre  = (float2*)(ob + 69206016);       // 2 MB  (end 71303168 < 134217728)

  prep_kernel<<<1024, 256, 0, stream>>>(nu_log, th_log, ga_log, B_re, B_im,
                                        C_re, C_im, Dmat, W_fc, W_proj,
                                        Wb, Wz, Wfc, Wp, lam);
  convert_x<<<M_SZ * DM / (256 * 4), 256, 0, stream>>>(x, S_all);

  // Bu = x @ [gamma*B_re ; gamma*B_im]^T   (M,512) bf16
  gemm_bt<256, 768, 512, 1, 4><<<(M_SZ / BM) * 4, 256, 0, stream>>>(S_all + 512, Wb, Bu, nullptr, nullptr);

  scan_carry <<<B_SZ * NCH, 256, 0, stream>>>(Bu, lam, carr);
  scan_prefix<<<B_SZ,       256, 0, stream>>>(carr, lam, pre);
  scan_apply <<<B_SZ * NCH, 256, 0, stream>>>(Bu, lam, pre, S_all);

  // z = Re(C s) + x D^T   -> bf16
  gemm_bt<768, 768, 256, 1, 2><<<(M_SZ / BM) * 2, 256, 0, stream>>>(S_all, Wz, Zbuf, nullptr, nullptr);
  // h = gelu(z W_fc + b_fc) -> bf16 (reuses Bu region)
  gemm_bt<256, 256, 1024, 2, 8><<<(M_SZ / BM) * 8, 256, 0, stream>>>(Zbuf, Wfc, Hbuf, b_fc, nullptr);
  // out = h W_proj + b_proj + x -> f32
  gemm_bt<1024, 1024, 256, 3, 2><<<(M_SZ / BM) * 2, 256, 0, stream>>>(Hbuf, Wp, d_out, b_proj, x);
}